// Round 3
// baseline (1437.228 us; speedup 1.0000x reference)
//
#include <hip/hip_runtime.h>
#include <hip/hip_bf16.h>

#define NN 100000
#define EE 1600000
#define GG 512
#define NB ((NN + 255) / 256)   // 391 blocks for node-sized scans

// ---- in-degree histogram (int) ----
__global__ void deg_kernel(const int* __restrict__ ei, int* __restrict__ cnt, int E_) {
    int e = blockIdx.x * 256 + threadIdx.x;
    if (e < E_) atomicAdd(&cnt[ei[E_ + e]], 1);
}

// ---- dinv = 1/sqrt(cnt + 1 self-loop) ----
__global__ void dinv_kernel(const int* __restrict__ cnt, float* __restrict__ dinv, int n) {
    int i = blockIdx.x * 256 + threadIdx.x;
    if (i < n) dinv[i] = rsqrtf((float)cnt[i] + 1.0f);
}

// ---- block sums for scan ----
__global__ void blocksum(const int* __restrict__ cnt, int* __restrict__ bsum) {
    __shared__ int sh[256];
    int i = blockIdx.x * 256 + threadIdx.x;
    sh[threadIdx.x] = (i < NN) ? cnt[i] : 0;
    __syncthreads();
    for (int o = 128; o > 0; o >>= 1) {
        if (threadIdx.x < o) sh[threadIdx.x] += sh[threadIdx.x + o];
        __syncthreads();
    }
    if (threadIdx.x == 0) bsum[blockIdx.x] = sh[0];
}

// ---- exclusive scan of block sums (1 block, 512 threads, nb<=512) ----
__global__ void scan_bsum(int* __restrict__ bsum, int nb) {
    __shared__ int sh[512];
    int t = threadIdx.x;
    int v = (t < nb) ? bsum[t] : 0;
    int orig = v;
    sh[t] = v;
    __syncthreads();
    for (int o = 1; o < 512; o <<= 1) {
        int add = (t >= o) ? sh[t - o] : 0;
        __syncthreads();
        sh[t] += add;
        __syncthreads();
    }
    if (t < nb) bsum[t] = sh[t] - orig;   // exclusive
}

// ---- final scan: row_ptr + cursor ----
__global__ void scan_final(const int* __restrict__ cnt, const int* __restrict__ boff,
                           int* __restrict__ row_ptr, int* __restrict__ cursor) {
    __shared__ int sh[256];
    int i = blockIdx.x * 256 + threadIdx.x;
    int v = (i < NN) ? cnt[i] : 0;
    int orig = v;
    sh[threadIdx.x] = v;
    __syncthreads();
    for (int o = 1; o < 256; o <<= 1) {
        int add = (threadIdx.x >= o) ? sh[threadIdx.x - o] : 0;
        __syncthreads();
        sh[threadIdx.x] += add;
        __syncthreads();
    }
    if (i < NN) {
        int ex = boff[blockIdx.x] + sh[threadIdx.x] - orig;
        row_ptr[i] = ex;
        cursor[i] = ex;
    }
    if (i == 0) row_ptr[NN] = EE;
}

// ---- fill CSR: packed (src-as-float, norm) per edge, bucketed by dst ----
__global__ void fill_csr(const int* __restrict__ ei, const float* __restrict__ dinv,
                         int* __restrict__ cursor, float2* __restrict__ ent, int E_) {
    int e = blockIdx.x * 256 + threadIdx.x;
    if (e < E_) {
        int s = ei[e], d = ei[E_ + e];
        int pos = atomicAdd(&cursor[d], 1);
        float2 v;
        v.x = __int_as_float(s);
        v.y = dinv[s] * dinv[d];
        ent[pos] = v;
    }
}

// ---- column stats: stats[0:64]=sum, stats[64:128]=sumsq ----
__global__ void colstats(const float* __restrict__ A, int nrows, float* __restrict__ stats) {
    __shared__ float ssum[4][64];
    __shared__ float ssq[4][64];
    int tid = threadIdx.x;
    int col = tid & 63, rg = tid >> 6;
    float s = 0.f, q = 0.f;
    for (int r = blockIdx.x * 4 + rg; r < nrows; r += gridDim.x * 4) {
        float v = A[r * 64 + col];
        s += v;
        q = fmaf(v, v, q);
    }
    ssum[rg][col] = s; ssq[rg][col] = q;
    __syncthreads();
    if (tid < 64) {
        float ts = ssum[0][tid] + ssum[1][tid] + ssum[2][tid] + ssum[3][tid];
        float tq = ssq[0][tid] + ssq[1][tid] + ssq[2][tid] + ssq[3][tid];
        atomicAdd(&stats[tid], ts);
        atomicAdd(&stats[64 + tid], tq);
    }
}

// ---- fold BN into weights ----
__global__ void prep(const float* __restrict__ stats, float count,
                     const float* __restrict__ g, const float* __restrict__ b,
                     const float* __restrict__ W, const float* __restrict__ basebias,
                     float* __restrict__ Wp, float* __restrict__ bp) {
    int j = threadIdx.x;  // 64 threads
    float acc = basebias ? basebias[j] : 0.f;
    for (int k = 0; k < 64; k++) {
        float mu  = stats[k] / count;
        float var = fmaxf(stats[64 + k] / count - mu * mu, 0.f);
        float rstd = rsqrtf(var + 1e-5f);
        float a = rstd * g[k];
        float w = W[k * 64 + j];
        Wp[k * 64 + j] = a * w;
        acc = fmaf(b[k] - mu * a, w, acc);
    }
    bp[j] = acc;
}

// ---- C = (relu?)(A@Wp + bp), optional fused column stats of C ----
__global__ __launch_bounds__(256) void gemm64(const float* __restrict__ A,
                                              const float* __restrict__ Wp,
                                              const float* __restrict__ bp,
                                              float* __restrict__ C, int nrows, int dorelu,
                                              float* __restrict__ stats) {
    __shared__ float Ws[64 * 64];
    __shared__ float As[64 * 64];
    __shared__ float ssh[256];
    __shared__ float qsh[256];
    int tid = threadIdx.x;
    int row0 = blockIdx.x * 64;
    for (int i = tid; i < 4096; i += 256) {
        Ws[i] = Wp[i];
        int r = row0 + (i >> 6);
        As[i] = (r < nrows) ? A[row0 * 64 + i] : 0.f;
    }
    __syncthreads();
    int col = tid & 63;
    int rg = tid >> 6;  // 0..3
    float bcol = bp[col];
    float s = 0.f, q = 0.f;
    for (int rr = rg; rr < 64; rr += 4) {
        int r = row0 + rr;
        if (r >= nrows) break;
        float acc = bcol;
#pragma unroll
        for (int k = 0; k < 64; k++) acc = fmaf(As[rr * 64 + k], Ws[k * 64 + col], acc);
        float v = dorelu ? fmaxf(acc, 0.f) : acc;
        C[r * 64 + col] = v;
        s += v;
        q = fmaf(v, v, q);
    }
    if (stats) {
        ssh[tid] = s; qsh[tid] = q;
        __syncthreads();
        if (tid < 64) {
            float ts = ssh[tid] + ssh[64 + tid] + ssh[128 + tid] + ssh[192 + tid];
            float tq = qsh[tid] + qsh[64 + tid] + qsh[128 + tid] + qsh[192 + tid];
            atomicAdd(&stats[tid], ts);
            atomicAdd(&stats[64 + tid], tq);
        }
    }
}

// ---- fused CSR gather, 8x MLP-unrolled edge loop ----
// hn = h + relu(dinv^2*m[i] + sum_e norm*m[src] + cb)
// optional: write h, accumulate next-layer BN stats, atomic pool.
// Grid MUST be exactly NN/16 blocks (NN divisible by 16).
__global__ __launch_bounds__(256) void gather(const int* __restrict__ row_ptr,
                                              const float2* __restrict__ ent,
                                              const float* __restrict__ dinv,
                                              const float* __restrict__ m,
                                              float* __restrict__ h,
                                              const float* __restrict__ cb,
                                              float* __restrict__ stats,
                                              float* __restrict__ pooled,
                                              const int* __restrict__ batch,
                                              int writeH) {
    int tid = threadIdx.x;
    int ng = tid >> 4;        // 16 nodes per block
    int cl = tid & 15;        // 16 col-groups of 4
    const float4* m4 = (const float4*)m;
    float4 cbv = ((const float4*)cb)[cl];
    int i = blockIdx.x * 16 + ng;

    float di = dinv[i];
    float4 mi = m4[i * 16 + cl];
    float d2 = di * di;
    float ax = d2 * mi.x, ay = d2 * mi.y, az = d2 * mi.z, aw = d2 * mi.w;
    int e = row_ptr[i], e1 = row_ptr[i + 1];

    // 8-wide: up to 8 independent row-gathers in flight
    for (; e + 8 <= e1; e += 8) {
        float2 c0 = ent[e + 0], c1 = ent[e + 1], c2 = ent[e + 2], c3 = ent[e + 3];
        float2 c4 = ent[e + 4], c5 = ent[e + 5], c6 = ent[e + 6], c7 = ent[e + 7];
        float4 r0 = m4[__float_as_int(c0.x) * 16 + cl];
        float4 r1 = m4[__float_as_int(c1.x) * 16 + cl];
        float4 r2 = m4[__float_as_int(c2.x) * 16 + cl];
        float4 r3 = m4[__float_as_int(c3.x) * 16 + cl];
        float4 r4 = m4[__float_as_int(c4.x) * 16 + cl];
        float4 r5 = m4[__float_as_int(c5.x) * 16 + cl];
        float4 r6 = m4[__float_as_int(c6.x) * 16 + cl];
        float4 r7 = m4[__float_as_int(c7.x) * 16 + cl];
        ax = fmaf(c0.y, r0.x, ax); ay = fmaf(c0.y, r0.y, ay); az = fmaf(c0.y, r0.z, az); aw = fmaf(c0.y, r0.w, aw);
        ax = fmaf(c1.y, r1.x, ax); ay = fmaf(c1.y, r1.y, ay); az = fmaf(c1.y, r1.z, az); aw = fmaf(c1.y, r1.w, aw);
        ax = fmaf(c2.y, r2.x, ax); ay = fmaf(c2.y, r2.y, ay); az = fmaf(c2.y, r2.z, az); aw = fmaf(c2.y, r2.w, aw);
        ax = fmaf(c3.y, r3.x, ax); ay = fmaf(c3.y, r3.y, ay); az = fmaf(c3.y, r3.z, az); aw = fmaf(c3.y, r3.w, aw);
        ax = fmaf(c4.y, r4.x, ax); ay = fmaf(c4.y, r4.y, ay); az = fmaf(c4.y, r4.z, az); aw = fmaf(c4.y, r4.w, aw);
        ax = fmaf(c5.y, r5.x, ax); ay = fmaf(c5.y, r5.y, ay); az = fmaf(c5.y, r5.z, az); aw = fmaf(c5.y, r5.w, aw);
        ax = fmaf(c6.y, r6.x, ax); ay = fmaf(c6.y, r6.y, ay); az = fmaf(c6.y, r6.z, az); aw = fmaf(c6.y, r6.w, aw);
        ax = fmaf(c7.y, r7.x, ax); ay = fmaf(c7.y, r7.y, ay); az = fmaf(c7.y, r7.z, az); aw = fmaf(c7.y, r7.w, aw);
    }
    if (e + 4 <= e1) {
        float2 c0 = ent[e + 0], c1 = ent[e + 1], c2 = ent[e + 2], c3 = ent[e + 3];
        float4 r0 = m4[__float_as_int(c0.x) * 16 + cl];
        float4 r1 = m4[__float_as_int(c1.x) * 16 + cl];
        float4 r2 = m4[__float_as_int(c2.x) * 16 + cl];
        float4 r3 = m4[__float_as_int(c3.x) * 16 + cl];
        ax = fmaf(c0.y, r0.x, ax); ay = fmaf(c0.y, r0.y, ay); az = fmaf(c0.y, r0.z, az); aw = fmaf(c0.y, r0.w, aw);
        ax = fmaf(c1.y, r1.x, ax); ay = fmaf(c1.y, r1.y, ay); az = fmaf(c1.y, r1.z, az); aw = fmaf(c1.y, r1.w, aw);
        ax = fmaf(c2.y, r2.x, ax); ay = fmaf(c2.y, r2.y, ay); az = fmaf(c2.y, r2.z, az); aw = fmaf(c2.y, r2.w, aw);
        ax = fmaf(c3.y, r3.x, ax); ay = fmaf(c3.y, r3.y, ay); az = fmaf(c3.y, r3.z, az); aw = fmaf(c3.y, r3.w, aw);
        e += 4;
    }
    for (; e < e1; e++) {
        float2 c = ent[e];
        float4 r = m4[__float_as_int(c.x) * 16 + cl];
        ax = fmaf(c.y, r.x, ax); ay = fmaf(c.y, r.y, ay);
        az = fmaf(c.y, r.z, az); aw = fmaf(c.y, r.w, aw);
    }

    float4 hb = ((const float4*)h)[i * 16 + cl];
    float nx = hb.x + fmaxf(ax + cbv.x, 0.f);
    float ny = hb.y + fmaxf(ay + cbv.y, 0.f);
    float nz = hb.z + fmaxf(az + cbv.z, 0.f);
    float nw = hb.w + fmaxf(aw + cbv.w, 0.f);
    if (writeH) {
        float4 o; o.x = nx; o.y = ny; o.z = nz; o.w = nw;
        ((float4*)h)[i * 16 + cl] = o;
    }
    if (pooled) {
        int g = batch[i];
        float* p = pooled + g * 64 + cl * 4;
        atomicAdd(p + 0, nx);
        atomicAdd(p + 1, ny);
        atomicAdd(p + 2, nz);
        atomicAdd(p + 3, nw);
    }
    if (stats) {
        __shared__ float rs[256 * 4];
        __shared__ float rq[256 * 4];
        rs[tid * 4 + 0] = nx; rs[tid * 4 + 1] = ny; rs[tid * 4 + 2] = nz; rs[tid * 4 + 3] = nw;
        rq[tid * 4 + 0] = nx * nx; rq[tid * 4 + 1] = ny * ny;
        rq[tid * 4 + 2] = nz * nz; rq[tid * 4 + 3] = nw * nw;
        __syncthreads();
        if (tid < 64) {  // tid = cl2*4+k -> column cl2*4+k
            int cl2 = tid >> 2, k = tid & 3;
            float a = 0.f, b = 0.f;
            for (int g = 0; g < 16; g++) {
                a += rs[(g * 16 + cl2) * 4 + k];
                b += rq[(g * 16 + cl2) * 4 + k];
            }
            atomicAdd(&stats[tid], a);
            atomicAdd(&stats[64 + tid], b);
        }
    }
}

// ---- final BN apply ----
__global__ void bn_apply(const float* __restrict__ A, const float* __restrict__ stats, float count,
                         const float* __restrict__ g, const float* __restrict__ b,
                         float* __restrict__ out, int total) {
    int idx = blockIdx.x * 256 + threadIdx.x;
    if (idx < total) {
        int j = idx & 63;
        float mu  = stats[j] / count;
        float var = fmaxf(stats[64 + j] / count - mu * mu, 0.f);
        float rstd = rsqrtf(var + 1e-5f);
        out[idx] = (A[idx] - mu) * rstd * g[j] + b[j];
    }
}

extern "C" void kernel_launch(void* const* d_in, const int* in_sizes, int n_in,
                              void* d_out, int out_size, void* d_ws, size_t ws_size,
                              hipStream_t stream) {
    const float* x     = (const float*)d_in[0];
    const int*   ei    = (const int*)d_in[1];
    const int*   batch = (const int*)d_in[2];
    const float* bnfg  = (const float*)d_in[3];
    const float* bnfb  = (const float*)d_in[4];
    const float* linW  = (const float*)d_in[5];
    const float* linb  = (const float*)d_in[6];
    const float* bncg  = (const float*)d_in[7];
    const float* bncb  = (const float*)d_in[8];
    const float* convW = (const float*)d_in[9];
    const float* convb = (const float*)d_in[10];
    const float* bnfcg = (const float*)d_in[11];
    const float* bnfcb = (const float*)d_in[12];
    const float* fcW   = (const float*)d_in[13];
    const float* fcb   = (const float*)d_in[14];
    const float* bnhg  = (const float*)d_in[15];
    const float* bnhb  = (const float*)d_in[16];

    const int N64 = NN * 64;
    float* ws = (float*)d_ws;
    size_t o = 0;
    int*    cnt     = (int*)(ws + o);    o += 100352;
    float*  dinv    = ws + o;            o += 100352;
    int*    row_ptr = (int*)(ws + o);    o += 100352;
    int*    cursor  = (int*)(ws + o);    o += 100352;
    int*    bsum    = (int*)(ws + o);    o += 512;
    float2* ent     = (float2*)(ws + o); o += 2 * (size_t)EE;
    float*  h       = ws + o;            o += N64;
    float*  m       = ws + o;            o += N64;
    float*  statsA  = ws + o;            o += 128;
    float*  statsB  = ws + o;            o += 128;
    float*  Wp      = ws + o;            o += 4096;
    float*  bp      = ws + o;            o += 64;
    float*  pa      = ws + o;            o += GG * 64;
    float*  pb      = ws + o;            o += GG * 64;

    // --- CSR build ---
    hipMemsetAsync(cnt, 0, NN * sizeof(int), stream);
    deg_kernel<<<(EE + 255) / 256, 256, 0, stream>>>(ei, cnt, EE);
    dinv_kernel<<<NB, 256, 0, stream>>>(cnt, dinv, NN);
    blocksum<<<NB, 256, 0, stream>>>(cnt, bsum);
    scan_bsum<<<1, 512, 0, stream>>>(bsum, NB);
    scan_final<<<NB, 256, 0, stream>>>(cnt, bsum, row_ptr, cursor);
    fill_csr<<<(EE + 255) / 256, 256, 0, stream>>>(ei, dinv, cursor, ent, EE);

    // --- stem: h = relu(BN(x)@linW + linb), fused stats(h) -> statsB ---
    hipMemsetAsync(statsA, 0, 512, stream);
    colstats<<<256, 256, 0, stream>>>(x, NN, statsA);
    prep<<<1, 64, 0, stream>>>(statsA, (float)NN, bnfg, bnfb, linW, linb, Wp, bp);
    hipMemsetAsync(statsB, 0, 512, stream);
    gemm64<<<(NN + 63) / 64, 256, 0, stream>>>(x, Wp, bp, h, NN, 1, statsB);

    // --- conv layers ---
    hipMemsetAsync(pa, 0, GG * 64 * sizeof(float), stream);
    float* cur = statsB; float* nxt = statsA;
    for (int l = 0; l < 4; l++) {
        prep<<<1, 64, 0, stream>>>(cur, (float)NN, bncg + 64 * l, bncb + 64 * l,
                                   convW + 4096 * l, nullptr, Wp, bp);
        gemm64<<<(NN + 63) / 64, 256, 0, stream>>>(h, Wp, bp, m, NN, 0, nullptr);
        if (l < 3) {
            hipMemsetAsync(nxt, 0, 512, stream);
            gather<<<NN / 16, 256, 0, stream>>>(row_ptr, ent, dinv, m, h,
                                                convb + 64 * l, nxt, nullptr, batch, 1);
        } else {
            gather<<<NN / 16, 256, 0, stream>>>(row_ptr, ent, dinv, m, h,
                                                convb + 64 * l, nullptr, pa, batch, 0);
        }
        float* t = cur; cur = nxt; nxt = t;
    }

    // --- fc head ---
    float* pin = pa; float* pout = pb;
    for (int i = 0; i < 2; i++) {
        hipMemsetAsync(statsA, 0, 512, stream);
        colstats<<<8, 256, 0, stream>>>(pin, GG, statsA);
        prep<<<1, 64, 0, stream>>>(statsA, (float)GG, bnfcg + 64 * i, bnfcb + 64 * i,
                                   fcW + 4096 * i, fcb + 64 * i, Wp, bp);
        gemm64<<<(GG + 63) / 64, 256, 0, stream>>>(pin, Wp, bp, pout, GG, 1, nullptr);
        float* t = pin; pin = pout; pout = t;
    }

    // --- final BN -> d_out ---
    hipMemsetAsync(statsA, 0, 512, stream);
    colstats<<<8, 256, 0, stream>>>(pin, GG, statsA);
    bn_apply<<<(GG * 64 + 255) / 256, 256, 0, stream>>>(pin, statsA, (float)GG, bnhg, bnhb,
                                                        (float*)d_out, GG * 64);
}

// Round 4
// 1300.214 us; speedup vs baseline: 1.1054x; 1.1054x over previous
//
#include <hip/hip_runtime.h>
#include <hip/hip_bf16.h>

#define NN 100000
#define EE 1600000
#define GG 512
#define NB ((NN + 255) / 256)   // 391 blocks for node-sized scans

// ---- in-degree histogram (int) ----
__global__ void deg_kernel(const int* __restrict__ ei, int* __restrict__ cnt, int E_) {
    int e = blockIdx.x * 256 + threadIdx.x;
    if (e < E_) atomicAdd(&cnt[ei[E_ + e]], 1);
}

// ---- dinv = 1/sqrt(cnt + 1 self-loop) ----
__global__ void dinv_kernel(const int* __restrict__ cnt, float* __restrict__ dinv, int n) {
    int i = blockIdx.x * 256 + threadIdx.x;
    if (i < n) dinv[i] = rsqrtf((float)cnt[i] + 1.0f);
}

// ---- block sums for scan ----
__global__ void blocksum(const int* __restrict__ cnt, int* __restrict__ bsum) {
    __shared__ int sh[256];
    int i = blockIdx.x * 256 + threadIdx.x;
    sh[threadIdx.x] = (i < NN) ? cnt[i] : 0;
    __syncthreads();
    for (int o = 128; o > 0; o >>= 1) {
        if (threadIdx.x < o) sh[threadIdx.x] += sh[threadIdx.x + o];
        __syncthreads();
    }
    if (threadIdx.x == 0) bsum[blockIdx.x] = sh[0];
}

// ---- exclusive scan of block sums (1 block, 512 threads, nb<=512) ----
__global__ void scan_bsum(int* __restrict__ bsum, int nb) {
    __shared__ int sh[512];
    int t = threadIdx.x;
    int v = (t < nb) ? bsum[t] : 0;
    int orig = v;
    sh[t] = v;
    __syncthreads();
    for (int o = 1; o < 512; o <<= 1) {
        int add = (t >= o) ? sh[t - o] : 0;
        __syncthreads();
        sh[t] += add;
        __syncthreads();
    }
    if (t < nb) bsum[t] = sh[t] - orig;   // exclusive
}

// ---- final scan: row_ptr + cursor ----
__global__ void scan_final(const int* __restrict__ cnt, const int* __restrict__ boff,
                           int* __restrict__ row_ptr, int* __restrict__ cursor) {
    __shared__ int sh[256];
    int i = blockIdx.x * 256 + threadIdx.x;
    int v = (i < NN) ? cnt[i] : 0;
    int orig = v;
    sh[threadIdx.x] = v;
    __syncthreads();
    for (int o = 1; o < 256; o <<= 1) {
        int add = (threadIdx.x >= o) ? sh[threadIdx.x - o] : 0;
        __syncthreads();
        sh[threadIdx.x] += add;
        __syncthreads();
    }
    if (i < NN) {
        int ex = boff[blockIdx.x] + sh[threadIdx.x] - orig;
        row_ptr[i] = ex;
        cursor[i] = ex;
    }
    if (i == 0) row_ptr[NN] = EE;
}

// ---- fill CSR: packed (src-as-float, norm) per edge, bucketed by dst ----
__global__ void fill_csr(const int* __restrict__ ei, const float* __restrict__ dinv,
                         int* __restrict__ cursor, float2* __restrict__ ent, int E_) {
    int e = blockIdx.x * 256 + threadIdx.x;
    if (e < E_) {
        int s = ei[e], d = ei[E_ + e];
        int pos = atomicAdd(&cursor[d], 1);
        float2 v;
        v.x = __int_as_float(s);
        v.y = dinv[s] * dinv[d];
        ent[pos] = v;
    }
}

// ---- column stats: stats[0:64]=sum, stats[64:128]=sumsq ----
__global__ void colstats(const float* __restrict__ A, int nrows, float* __restrict__ stats) {
    __shared__ float ssum[4][64];
    __shared__ float ssq[4][64];
    int tid = threadIdx.x;
    int col = tid & 63, rg = tid >> 6;
    float s = 0.f, q = 0.f;
    for (int r = blockIdx.x * 4 + rg; r < nrows; r += gridDim.x * 4) {
        float v = A[r * 64 + col];
        s += v;
        q = fmaf(v, v, q);
    }
    ssum[rg][col] = s; ssq[rg][col] = q;
    __syncthreads();
    if (tid < 64) {
        float ts = ssum[0][tid] + ssum[1][tid] + ssum[2][tid] + ssum[3][tid];
        float tq = ssq[0][tid] + ssq[1][tid] + ssq[2][tid] + ssq[3][tid];
        atomicAdd(&stats[tid], ts);
        atomicAdd(&stats[64 + tid], tq);
    }
}

// ---- fold BN into weights ----
__global__ void prep(const float* __restrict__ stats, float count,
                     const float* __restrict__ g, const float* __restrict__ b,
                     const float* __restrict__ W, const float* __restrict__ basebias,
                     float* __restrict__ Wp, float* __restrict__ bp) {
    int j = threadIdx.x;  // 64 threads
    float acc = basebias ? basebias[j] : 0.f;
    for (int k = 0; k < 64; k++) {
        float mu  = stats[k] / count;
        float var = fmaxf(stats[64 + k] / count - mu * mu, 0.f);
        float rstd = rsqrtf(var + 1e-5f);
        float a = rstd * g[k];
        float w = W[k * 64 + j];
        Wp[k * 64 + j] = a * w;
        acc = fmaf(b[k] - mu * a, w, acc);
    }
    bp[j] = acc;
}

// ---- C = (relu?)(A@Wp + bp); fp32 out (C) and/or bf16 out (Cb); optional fused stats ----
__global__ __launch_bounds__(256) void gemm64(const float* __restrict__ A,
                                              const float* __restrict__ Wp,
                                              const float* __restrict__ bp,
                                              float* __restrict__ C,
                                              __hip_bfloat16* __restrict__ Cb,
                                              int nrows, int dorelu,
                                              float* __restrict__ stats) {
    __shared__ float Ws[64 * 64];
    __shared__ float As[64 * 64];
    __shared__ float ssh[256];
    __shared__ float qsh[256];
    int tid = threadIdx.x;
    int row0 = blockIdx.x * 64;
    const float4* A4 = (const float4*)(A + (size_t)row0 * 64);
    const float4* W4 = (const float4*)Wp;
    for (int i = tid; i < 1024; i += 256) {
        ((float4*)Ws)[i] = W4[i];
        int r = row0 + (i >> 4);
        float4 v;
        if (r < nrows) v = A4[i];
        else { v.x = v.y = v.z = v.w = 0.f; }
        ((float4*)As)[i] = v;
    }
    __syncthreads();
    int col = tid & 63;
    int rg = tid >> 6;  // 0..3
    float bcol = bp[col];
    float s = 0.f, q = 0.f;
    for (int rr = rg; rr < 64; rr += 4) {
        int r = row0 + rr;
        if (r >= nrows) break;
        float acc = bcol;
#pragma unroll
        for (int k = 0; k < 64; k++) acc = fmaf(As[rr * 64 + k], Ws[k * 64 + col], acc);
        float v = dorelu ? fmaxf(acc, 0.f) : acc;
        if (C)  C[(size_t)r * 64 + col] = v;
        if (Cb) Cb[(size_t)r * 64 + col] = __float2bfloat16(v);
        s += v;
        q = fmaf(v, v, q);
    }
    if (stats) {
        ssh[tid] = s; qsh[tid] = q;
        __syncthreads();
        if (tid < 64) {
            float ts = ssh[tid] + ssh[64 + tid] + ssh[128 + tid] + ssh[192 + tid];
            float tq = qsh[tid] + qsh[64 + tid] + qsh[128 + tid] + qsh[192 + tid];
            atomicAdd(&stats[tid], ts);
            atomicAdd(&stats[64 + tid], tq);
        }
    }
}

#define UNPACK8(Q, F0, F1, F2, F3, F4, F5, F6, F7)                         \
    F0 = __uint_as_float((Q).x << 16); F1 = __uint_as_float((Q).x & 0xffff0000u); \
    F2 = __uint_as_float((Q).y << 16); F3 = __uint_as_float((Q).y & 0xffff0000u); \
    F4 = __uint_as_float((Q).z << 16); F5 = __uint_as_float((Q).z & 0xffff0000u); \
    F6 = __uint_as_float((Q).w << 16); F7 = __uint_as_float((Q).w & 0xffff0000u);

#define FMA8(W, Q)                                                          \
    { float f0, f1, f2, f3, f4, f5, f6, f7; UNPACK8(Q, f0, f1, f2, f3, f4, f5, f6, f7); \
      a0 = fmaf((W), f0, a0); a1 = fmaf((W), f1, a1); a2 = fmaf((W), f2, a2); a3 = fmaf((W), f3, a3); \
      a4 = fmaf((W), f4, a4); a5 = fmaf((W), f5, a5); a6 = fmaf((W), f6, a6); a7 = fmaf((W), f7, a7); }

// ---- fused CSR gather over bf16 m rows (128 B each), 8 lanes/node x 8 cols ----
// hn = h + relu(dinv^2*m[i] + sum_e norm*m[src] + cb); optional writeH / stats / pool.
// Grid MUST be exactly NN/32 blocks.
__global__ __launch_bounds__(256) void gather(const int* __restrict__ row_ptr,
                                              const float2* __restrict__ ent,
                                              const float* __restrict__ dinv,
                                              const uint4* __restrict__ mq,
                                              float* __restrict__ h,
                                              const float* __restrict__ cb,
                                              float* __restrict__ stats,
                                              float* __restrict__ pooled,
                                              const int* __restrict__ batch,
                                              int writeH) {
    int tid = threadIdx.x;
    int ng = tid >> 3;        // 32 nodes per block
    int li = tid & 7;         // 8 lanes per node; lane covers cols li*8..li*8+7
    int i = blockIdx.x * 32 + ng;

    float a0, a1, a2, a3, a4, a5, a6, a7;
    {
        float di = dinv[i];
        float d2 = di * di;
        uint4 qs = mq[i * 8 + li];
        float f0, f1, f2, f3, f4, f5, f6, f7;
        UNPACK8(qs, f0, f1, f2, f3, f4, f5, f6, f7);
        a0 = d2 * f0; a1 = d2 * f1; a2 = d2 * f2; a3 = d2 * f3;
        a4 = d2 * f4; a5 = d2 * f5; a6 = d2 * f6; a7 = d2 * f7;
    }
    int e = row_ptr[i], e1 = row_ptr[i + 1];

    float2 c0, c1, c2, c3, c4, c5, c6, c7;
    if (e + 8 <= e1) {
        c0 = ent[e + 0]; c1 = ent[e + 1]; c2 = ent[e + 2]; c3 = ent[e + 3];
        c4 = ent[e + 4]; c5 = ent[e + 5]; c6 = ent[e + 6]; c7 = ent[e + 7];
    }
    while (e + 8 <= e1) {
        uint4 r0 = mq[__float_as_int(c0.x) * 8 + li];
        uint4 r1 = mq[__float_as_int(c1.x) * 8 + li];
        uint4 r2 = mq[__float_as_int(c2.x) * 8 + li];
        uint4 r3 = mq[__float_as_int(c3.x) * 8 + li];
        uint4 r4 = mq[__float_as_int(c4.x) * 8 + li];
        uint4 r5 = mq[__float_as_int(c5.x) * 8 + li];
        uint4 r6 = mq[__float_as_int(c6.x) * 8 + li];
        uint4 r7 = mq[__float_as_int(c7.x) * 8 + li];
        float w0 = c0.y, w1 = c1.y, w2 = c2.y, w3 = c3.y;
        float w4 = c4.y, w5 = c5.y, w6 = c6.y, w7 = c7.y;
        e += 8;
        if (e + 8 <= e1) {   // prefetch next ent chunk while rows are in flight
            c0 = ent[e + 0]; c1 = ent[e + 1]; c2 = ent[e + 2]; c3 = ent[e + 3];
            c4 = ent[e + 4]; c5 = ent[e + 5]; c6 = ent[e + 6]; c7 = ent[e + 7];
        }
        FMA8(w0, r0); FMA8(w1, r1); FMA8(w2, r2); FMA8(w3, r3);
        FMA8(w4, r4); FMA8(w5, r5); FMA8(w6, r6); FMA8(w7, r7);
    }
    for (; e < e1; e++) {
        float2 c = ent[e];
        uint4 r = mq[__float_as_int(c.x) * 8 + li];
        FMA8(c.y, r);
    }

    const float4* h4 = (const float4*)h;
    float4 hb0 = h4[(size_t)i * 16 + li * 2];
    float4 hb1 = h4[(size_t)i * 16 + li * 2 + 1];
    float4 cb0 = ((const float4*)cb)[li * 2];
    float4 cb1 = ((const float4*)cb)[li * 2 + 1];
    float n0 = hb0.x + fmaxf(a0 + cb0.x, 0.f);
    float n1 = hb0.y + fmaxf(a1 + cb0.y, 0.f);
    float n2 = hb0.z + fmaxf(a2 + cb0.z, 0.f);
    float n3 = hb0.w + fmaxf(a3 + cb0.w, 0.f);
    float n4 = hb1.x + fmaxf(a4 + cb1.x, 0.f);
    float n5 = hb1.y + fmaxf(a5 + cb1.y, 0.f);
    float n6 = hb1.z + fmaxf(a6 + cb1.z, 0.f);
    float n7 = hb1.w + fmaxf(a7 + cb1.w, 0.f);
    if (writeH) {
        float4 o0; o0.x = n0; o0.y = n1; o0.z = n2; o0.w = n3;
        float4 o1; o1.x = n4; o1.y = n5; o1.z = n6; o1.w = n7;
        ((float4*)h)[(size_t)i * 16 + li * 2] = o0;
        ((float4*)h)[(size_t)i * 16 + li * 2 + 1] = o1;
    }
    if (pooled) {
        int g = batch[i];
        float* p = pooled + g * 64 + li * 8;
        atomicAdd(p + 0, n0); atomicAdd(p + 1, n1);
        atomicAdd(p + 2, n2); atomicAdd(p + 3, n3);
        atomicAdd(p + 4, n4); atomicAdd(p + 5, n5);
        atomicAdd(p + 6, n6); atomicAdd(p + 7, n7);
    }
    if (stats) {
        __shared__ float rs[2048];
        __shared__ float rq[2048];
        int base = ng * 64 + li * 8;
        rs[base + 0] = n0; rs[base + 1] = n1; rs[base + 2] = n2; rs[base + 3] = n3;
        rs[base + 4] = n4; rs[base + 5] = n5; rs[base + 6] = n6; rs[base + 7] = n7;
        rq[base + 0] = n0 * n0; rq[base + 1] = n1 * n1; rq[base + 2] = n2 * n2; rq[base + 3] = n3 * n3;
        rq[base + 4] = n4 * n4; rq[base + 5] = n5 * n5; rq[base + 6] = n6 * n6; rq[base + 7] = n7 * n7;
        __syncthreads();
        if (tid < 64) {
            float a = 0.f, b = 0.f;
            for (int g2 = 0; g2 < 32; g2++) {
                a += rs[g2 * 64 + tid];
                b += rq[g2 * 64 + tid];
            }
            atomicAdd(&stats[tid], a);
            atomicAdd(&stats[64 + tid], b);
        }
    }
}

// ---- final BN apply ----
__global__ void bn_apply(const float* __restrict__ A, const float* __restrict__ stats, float count,
                         const float* __restrict__ g, const float* __restrict__ b,
                         float* __restrict__ out, int total) {
    int idx = blockIdx.x * 256 + threadIdx.x;
    if (idx < total) {
        int j = idx & 63;
        float mu  = stats[j] / count;
        float var = fmaxf(stats[64 + j] / count - mu * mu, 0.f);
        float rstd = rsqrtf(var + 1e-5f);
        out[idx] = (A[idx] - mu) * rstd * g[j] + b[j];
    }
}

extern "C" void kernel_launch(void* const* d_in, const int* in_sizes, int n_in,
                              void* d_out, int out_size, void* d_ws, size_t ws_size,
                              hipStream_t stream) {
    const float* x     = (const float*)d_in[0];
    const int*   ei    = (const int*)d_in[1];
    const int*   batch = (const int*)d_in[2];
    const float* bnfg  = (const float*)d_in[3];
    const float* bnfb  = (const float*)d_in[4];
    const float* linW  = (const float*)d_in[5];
    const float* linb  = (const float*)d_in[6];
    const float* bncg  = (const float*)d_in[7];
    const float* bncb  = (const float*)d_in[8];
    const float* convW = (const float*)d_in[9];
    const float* convb = (const float*)d_in[10];
    const float* bnfcg = (const float*)d_in[11];
    const float* bnfcb = (const float*)d_in[12];
    const float* fcW   = (const float*)d_in[13];
    const float* fcb   = (const float*)d_in[14];
    const float* bnhg  = (const float*)d_in[15];
    const float* bnhb  = (const float*)d_in[16];

    const int N64 = NN * 64;
    float* ws = (float*)d_ws;
    size_t o = 0;
    int*    cnt     = (int*)(ws + o);    o += 100352;
    float*  dinv    = ws + o;            o += 100352;
    int*    row_ptr = (int*)(ws + o);    o += 100352;
    int*    cursor  = (int*)(ws + o);    o += 100352;
    int*    bsum    = (int*)(ws + o);    o += 512;
    float2* ent     = (float2*)(ws + o); o += 2 * (size_t)EE;
    float*  h       = ws + o;            o += N64;
    __hip_bfloat16* mb = (__hip_bfloat16*)(ws + o); o += N64 / 2;  // bf16 m
    float*  statsA  = ws + o;            o += 128;
    float*  statsB  = ws + o;            o += 128;
    float*  Wp      = ws + o;            o += 4096;
    float*  bp      = ws + o;            o += 64;
    float*  pa      = ws + o;            o += GG * 64;
    float*  pb      = ws + o;            o += GG * 64;

    // --- CSR build ---
    hipMemsetAsync(cnt, 0, NN * sizeof(int), stream);
    deg_kernel<<<(EE + 255) / 256, 256, 0, stream>>>(ei, cnt, EE);
    dinv_kernel<<<NB, 256, 0, stream>>>(cnt, dinv, NN);
    blocksum<<<NB, 256, 0, stream>>>(cnt, bsum);
    scan_bsum<<<1, 512, 0, stream>>>(bsum, NB);
    scan_final<<<NB, 256, 0, stream>>>(cnt, bsum, row_ptr, cursor);
    fill_csr<<<(EE + 255) / 256, 256, 0, stream>>>(ei, dinv, cursor, ent, EE);

    // --- stem: h = relu(BN(x)@linW + linb), fused stats(h) -> statsB ---
    hipMemsetAsync(statsA, 0, 512, stream);
    colstats<<<256, 256, 0, stream>>>(x, NN, statsA);
    prep<<<1, 64, 0, stream>>>(statsA, (float)NN, bnfg, bnfb, linW, linb, Wp, bp);
    hipMemsetAsync(statsB, 0, 512, stream);
    gemm64<<<(NN + 63) / 64, 256, 0, stream>>>(x, Wp, bp, h, nullptr, NN, 1, statsB);

    // --- conv layers ---
    hipMemsetAsync(pa, 0, GG * 64 * sizeof(float), stream);
    float* cur = statsB; float* nxt = statsA;
    for (int l = 0; l < 4; l++) {
        prep<<<1, 64, 0, stream>>>(cur, (float)NN, bncg + 64 * l, bncb + 64 * l,
                                   convW + 4096 * l, nullptr, Wp, bp);
        gemm64<<<(NN + 63) / 64, 256, 0, stream>>>(h, Wp, bp, nullptr, mb, NN, 0, nullptr);
        if (l < 3) {
            hipMemsetAsync(nxt, 0, 512, stream);
            gather<<<NN / 32, 256, 0, stream>>>(row_ptr, ent, dinv, (const uint4*)mb, h,
                                                convb + 64 * l, nxt, nullptr, batch, 1);
        } else {
            gather<<<NN / 32, 256, 0, stream>>>(row_ptr, ent, dinv, (const uint4*)mb, h,
                                                convb + 64 * l, nullptr, pa, batch, 0);
        }
        float* t = cur; cur = nxt; nxt = t;
    }

    // --- fc head ---
    float* pin = pa; float* pout = pb;
    for (int i = 0; i < 2; i++) {
        hipMemsetAsync(statsA, 0, 512, stream);
        colstats<<<8, 256, 0, stream>>>(pin, GG, statsA);
        prep<<<1, 64, 0, stream>>>(statsA, (float)GG, bnfcg + 64 * i, bnfcb + 64 * i,
                                   fcW + 4096 * i, fcb + 64 * i, Wp, bp);
        gemm64<<<(GG + 63) / 64, 256, 0, stream>>>(pin, Wp, bp, pout, nullptr, GG, 1, nullptr);
        float* t = pin; pin = pout; pout = t;
    }

    // --- final BN -> d_out ---
    hipMemsetAsync(statsA, 0, 512, stream);
    colstats<<<8, 256, 0, stream>>>(pin, GG, statsA);
    bn_apply<<<(GG * 64 + 255) / 256, 256, 0, stream>>>(pin, statsA, (float)GG, bnhg, bnhb,
                                                        (float*)d_out, GG * 64);
}